// Round 12
// baseline (43.187 us; speedup 1.0000x reference)
//
#include <hip/hip_runtime.h>
#include <math.h>

#define QN 8
#define NDIMS 2
#define LATENT 64
#define OUTC 32     // Q + Q + Q*NDIMS
#define IT 8        // i-rows per block tile in pair kernel
#define JPT 2       // j's per thread in pair kernel

// ---------------------------------------------------------------------------
// Phase 1: feature MLP — BYTE-IDENTICAL to round 11.
// ---------------------------------------------------------------------------
__global__ __launch_bounds__(256) void feat_kernel(
    const float* __restrict__ x, const float* __restrict__ y, int n,
    const float* __restrict__ W1, const float* __restrict__ b1,
    const float* __restrict__ W2, const float* __restrict__ b2,
    float* __restrict__ featX, float* __restrict__ featY)
{
    const int t    = blockIdx.x * 256 + threadIdx.x;
    const int pt   = t >> 5;                 // point index (2 points per wave)
    const int o    = t & 31;                 // output unit for this lane
    const int npts = 2 * n;
    if (pt >= npts) return;

    const float* p = (pt < n) ? (x + 2 * pt) : (y + 2 * (pt - n));
    float p0 = p[0], p1 = p[1];

    const float kScale = 1.0507009873554804934193349852946f;
    const float kAlpha = 1.6732632423543772848170429916717f;

    const float4* w2v = (const float4*)(W2 + o * LATENT);
    float z0 = b2[o], z1 = 0.f, z2 = 0.f, z3 = 0.f;
    #pragma unroll
    for (int c = 0; c < LATENT / 16; ++c) {
        float hb[16];
        #pragma unroll
        for (int r = 0; r < 16; ++r) {
            int k = 16 * c + r;
            float zz = fmaf(W1[2 * k], p0, fmaf(W1[2 * k + 1], p1, b1[k]));
            hb[r] = kScale * (zz > 0.f ? zz : kAlpha * (__expf(zz) - 1.f));
        }
        float4 w0 = w2v[4 * c + 0];
        float4 w1v = w2v[4 * c + 1];
        float4 w2q = w2v[4 * c + 2];
        float4 w3 = w2v[4 * c + 3];
        z0 = fmaf(w0.x,  hb[0],  fmaf(w0.y,  hb[1],  fmaf(w0.z,  hb[2],  fmaf(w0.w,  hb[3],  z0))));
        z1 = fmaf(w1v.x, hb[4],  fmaf(w1v.y, hb[5],  fmaf(w1v.z, hb[6],  fmaf(w1v.w, hb[7],  z1))));
        z2 = fmaf(w2q.x, hb[8],  fmaf(w2q.y, hb[9],  fmaf(w2q.z, hb[10], fmaf(w2q.w, hb[11], z2))));
        z3 = fmaf(w3.x,  hb[12], fmaf(w3.y,  hb[13], fmaf(w3.z,  hb[14], fmaf(w3.w,  hb[15], z3))));
    }
    float z = (z0 + z1) + (z2 + z3);
    float av = fmaxf(z, 0.f) + __logf(1.f + __expf(-fabsf(z)));

    const int lane = threadIdx.x & 63;
    const int base = lane & 32;               // half-wave owning this point
    const int q    = lane & 7;
    float w_ = __shfl(av, base + q, 64);
    float s_ = __shfl(av, base + 8 + q, 64);
    float f0 = __shfl(av, base + 16 + 2 * q, 64);
    float f1 = __shfl(av, base + 17 + 2 * q, 64);

    if ((lane & 31) < 8) {
        const float TWO_PI  = 6.283185307179586f;
        const float ROOT4_2 = 1.18920711500272107f;   // 2^(1/4)
        float phi = fmaf(f0, p0, f1 * p1);
        float rr  = phi - floorf(phi);
        float ang = TWO_PI * rr;
        float* fo = (pt < n) ? (featX + 32 * pt) : (featY + 32 * (pt - n));
        fo[q]          = w_ * sqrtf(s_) * ROOT4_2;
        fo[QN + q]     = s_ * s_;
        fo[2 * QN + q] = __cosf(ang);
        fo[3 * QN + q] = __sinf(ang);
    }
}

// ---------------------------------------------------------------------------
// Phase 2: pair_v3 — BYTE-IDENTICAL to round 11 (JPT=2, IT=8).
// ---------------------------------------------------------------------------
__global__ __launch_bounds__(256) void pair_kernel(
    const float* __restrict__ x, const float* __restrict__ y, int n,
    const float* __restrict__ fA, const float* __restrict__ fB,
    float* __restrict__ out)
{
    __shared__ __align__(16) float faS[IT * 32];       // 1 KB
    __shared__ __align__(16) float xaS[IT * 2];        // 64 B

    const int tid = threadIdx.x;
    const int i0  = blockIdx.y * IT;

    if (tid < IT * 8) {                                 // 64 float4s of fA
        ((float4*)faS)[tid] = ((const float4*)(fA + (size_t)i0 * 32))[tid];
    } else if (tid < IT * 8 + IT / 2) {                 // 4 float4s of x
        ((float4*)xaS)[tid - IT * 8] = ((const float4*)(x + 2 * i0))[tid - IT * 8];
    }
    __syncthreads();

    const int j0 = blockIdx.x * (256 * JPT) + tid * JPT;   // 2 contiguous j's
    if (j0 >= n) return;     // no barriers after this point

    float uB[JPT][QN], ssB[JPT][QN], cB[JPT][QN], snB[JPT][QN];
    float yj0[JPT], yj1[JPT];
    #pragma unroll
    for (int jj = 0; jj < JPT; ++jj) {
        const float4* fb4 = (const float4*)(fB + 32 * (j0 + jj));
        float4 a0 = fb4[0], a1 = fb4[1], a2 = fb4[2], a3 = fb4[3];
        float4 a4 = fb4[4], a5 = fb4[5], a6 = fb4[6], a7 = fb4[7];
        uB[jj][0]=a0.x; uB[jj][1]=a0.y; uB[jj][2]=a0.z; uB[jj][3]=a0.w;
        uB[jj][4]=a1.x; uB[jj][5]=a1.y; uB[jj][6]=a1.z; uB[jj][7]=a1.w;
        ssB[jj][0]=a2.x; ssB[jj][1]=a2.y; ssB[jj][2]=a2.z; ssB[jj][3]=a2.w;
        ssB[jj][4]=a3.x; ssB[jj][5]=a3.y; ssB[jj][6]=a3.z; ssB[jj][7]=a3.w;
        cB[jj][0]=a4.x; cB[jj][1]=a4.y; cB[jj][2]=a4.z; cB[jj][3]=a4.w;
        cB[jj][4]=a5.x; cB[jj][5]=a5.y; cB[jj][6]=a5.z; cB[jj][7]=a5.w;
        snB[jj][0]=a6.x; snB[jj][1]=a6.y; snB[jj][2]=a6.z; snB[jj][3]=a6.w;
        snB[jj][4]=a7.x; snB[jj][5]=a7.y; snB[jj][6]=a7.z; snB[jj][7]=a7.w;
        float2 yv = *(const float2*)(y + 2 * (j0 + jj));
        yj0[jj] = yv.x; yj1[jj] = yv.y;
    }

    const float NLOG2E = -1.4426950408889634f;

    #pragma unroll 2
    for (int ii = 0; ii < IT; ++ii) {
        int i = i0 + ii;
        if (i >= n) break;

        const float4* fa4 = (const float4*)(faS + ii * 32);
        float4 b0 = fa4[0], b1v = fa4[1], b2v = fa4[2], b3 = fa4[3];
        float4 b4 = fa4[4], b5 = fa4[5], b6 = fa4[6], b7 = fa4[7];
        float uA[QN]  = {b0.x,b0.y,b0.z,b0.w, b1v.x,b1v.y,b1v.z,b1v.w};
        float ssA[QN] = {b2v.x,b2v.y,b2v.z,b2v.w, b3.x,b3.y,b3.z,b3.w};
        float cA[QN]  = {b4.x,b4.y,b4.z,b4.w, b5.x,b5.y,b5.z,b5.w};
        float snA[QN] = {b6.x,b6.y,b6.z,b6.w, b7.x,b7.y,b7.z,b7.w};
        float xi0 = xaS[2 * ii], xi1 = xaS[2 * ii + 1];

        float d2ln[JPT];
        #pragma unroll
        for (int jj = 0; jj < JPT; ++jj) {
            float dx = xi0 - yj0[jj];
            float dy = xi1 - yj1[jj];
            d2ln[jj] = fmaf(dx, dx, dy * dy) * NLOG2E;   // -d2*log2(e)
        }

        float2 accv;
        float* accp = &accv.x;
        #pragma unroll
        for (int jj = 0; jj < JPT; ++jj) {
            float acc = 0.f;
            #pragma unroll
            for (int q = 0; q < QN; ++q) {
                float s2  = ssA[q] + ssB[jj][q];
                float inv = __builtin_amdgcn_rcpf(s2);
                float e   = __builtin_amdgcn_exp2f(d2ln[jj] * inv);
                float t   = uA[q] * uB[jj][q];
                float c   = fmaf(cA[q], cB[jj][q], snA[q] * snB[jj][q]);
                acc = fmaf(t * inv * e, c, acc);
            }
            accp[jj] = acc;
        }
        *(float2*)(out + (long)i * n + j0) = accv;
    }
}

extern "C" void kernel_launch(void* const* d_in, const int* in_sizes, int n_in,
                              void* d_out, int out_size, void* d_ws, size_t ws_size,
                              hipStream_t stream)
{
    const float* x  = (const float*)d_in[0];
    const float* y  = (const float*)d_in[1];
    const float* W1 = (const float*)d_in[2];
    const float* b1 = (const float*)d_in[3];
    const float* W2 = (const float*)d_in[4];
    const float* b2 = (const float*)d_in[5];
    float* out = (float*)d_out;

    int n = in_sizes[0] / NDIMS;     // 2048

    float* featX = (float*)d_ws;
    float* featY = featX + (size_t)n * 32;

    int npts = 2 * n;
    int featThreads = npts * OUTC;                    // one thread per (pt, o)
    hipLaunchKernelGGL(feat_kernel, dim3((featThreads + 255) / 256), dim3(256), 0, stream,
                       x, y, n, W1, b1, W2, b2, featX, featY);

    dim3 grid((n + 256 * JPT - 1) / (256 * JPT), (n + IT - 1) / IT);
    hipLaunchKernelGGL(pair_kernel, grid, dim3(256), 0, stream,
                       x, y, n, featX, featY, out);

    // INSTRUMENTATION (deterministic, idempotent): second identical pair
    // launch writes the same bytes to d_out. dur_delta vs r11 (27.1us) =
    // in-graph duration of pair + one launch overhead. Splits the 27us
    // budget between feat and pair, which rocprof cannot see (poison-fill
    // dispatches mask both kernels in every capture).
    hipLaunchKernelGGL(pair_kernel, grid, dim3(256), 0, stream,
                       x, y, n, featX, featY, out);
}

// Round 13
// 39.265 us; speedup vs baseline: 1.0999x; 1.0999x over previous
//
#include <hip/hip_runtime.h>
#include <math.h>

#define QN 8
#define NDIMS 2
#define LATENT 64
#define OUTC 32     // Q + Q + Q*NDIMS
#define IT 8        // i-rows per block tile in pair kernel
#define JPT 2       // j's per thread in pair kernel

// ---------------------------------------------------------------------------
// Phase 1: feature MLP — BYTE-IDENTICAL to round 11.
// ---------------------------------------------------------------------------
__global__ __launch_bounds__(256) void feat_kernel(
    const float* __restrict__ x, const float* __restrict__ y, int n,
    const float* __restrict__ W1, const float* __restrict__ b1,
    const float* __restrict__ W2, const float* __restrict__ b2,
    float* __restrict__ featX, float* __restrict__ featY)
{
    const int t    = blockIdx.x * 256 + threadIdx.x;
    const int pt   = t >> 5;                 // point index (2 points per wave)
    const int o    = t & 31;                 // output unit for this lane
    const int npts = 2 * n;
    if (pt >= npts) return;

    const float* p = (pt < n) ? (x + 2 * pt) : (y + 2 * (pt - n));
    float p0 = p[0], p1 = p[1];

    const float kScale = 1.0507009873554804934193349852946f;
    const float kAlpha = 1.6732632423543772848170429916717f;

    const float4* w2v = (const float4*)(W2 + o * LATENT);
    float z0 = b2[o], z1 = 0.f, z2 = 0.f, z3 = 0.f;
    #pragma unroll
    for (int c = 0; c < LATENT / 16; ++c) {
        float hb[16];
        #pragma unroll
        for (int r = 0; r < 16; ++r) {
            int k = 16 * c + r;
            float zz = fmaf(W1[2 * k], p0, fmaf(W1[2 * k + 1], p1, b1[k]));
            hb[r] = kScale * (zz > 0.f ? zz : kAlpha * (__expf(zz) - 1.f));
        }
        float4 w0 = w2v[4 * c + 0];
        float4 w1v = w2v[4 * c + 1];
        float4 w2q = w2v[4 * c + 2];
        float4 w3 = w2v[4 * c + 3];
        z0 = fmaf(w0.x,  hb[0],  fmaf(w0.y,  hb[1],  fmaf(w0.z,  hb[2],  fmaf(w0.w,  hb[3],  z0))));
        z1 = fmaf(w1v.x, hb[4],  fmaf(w1v.y, hb[5],  fmaf(w1v.z, hb[6],  fmaf(w1v.w, hb[7],  z1))));
        z2 = fmaf(w2q.x, hb[8],  fmaf(w2q.y, hb[9],  fmaf(w2q.z, hb[10], fmaf(w2q.w, hb[11], z2))));
        z3 = fmaf(w3.x,  hb[12], fmaf(w3.y,  hb[13], fmaf(w3.z,  hb[14], fmaf(w3.w,  hb[15], z3))));
    }
    float z = (z0 + z1) + (z2 + z3);
    float av = fmaxf(z, 0.f) + __logf(1.f + __expf(-fabsf(z)));

    const int lane = threadIdx.x & 63;
    const int base = lane & 32;               // half-wave owning this point
    const int q    = lane & 7;
    float w_ = __shfl(av, base + q, 64);
    float s_ = __shfl(av, base + 8 + q, 64);
    float f0 = __shfl(av, base + 16 + 2 * q, 64);
    float f1 = __shfl(av, base + 17 + 2 * q, 64);

    if ((lane & 31) < 8) {
        const float TWO_PI  = 6.283185307179586f;
        const float ROOT4_2 = 1.18920711500272107f;   // 2^(1/4)
        float phi = fmaf(f0, p0, f1 * p1);
        float rr  = phi - floorf(phi);
        float ang = TWO_PI * rr;
        float* fo = (pt < n) ? (featX + 32 * pt) : (featY + 32 * (pt - n));
        fo[q]          = w_ * sqrtf(s_) * ROOT4_2;
        fo[QN + q]     = s_ * s_;
        fo[2 * QN + q] = __cosf(ang);
        fo[3 * QN + q] = __sinf(ang);
    }
}

// ---------------------------------------------------------------------------
// Phase 2: pair_v3 — BYTE-IDENTICAL to round 11 (JPT=2, IT=8).
// ---------------------------------------------------------------------------
__global__ __launch_bounds__(256) void pair_kernel(
    const float* __restrict__ x, const float* __restrict__ y, int n,
    const float* __restrict__ fA, const float* __restrict__ fB,
    float* __restrict__ out)
{
    __shared__ __align__(16) float faS[IT * 32];       // 1 KB
    __shared__ __align__(16) float xaS[IT * 2];        // 64 B

    const int tid = threadIdx.x;
    const int i0  = blockIdx.y * IT;

    if (tid < IT * 8) {                                 // 64 float4s of fA
        ((float4*)faS)[tid] = ((const float4*)(fA + (size_t)i0 * 32))[tid];
    } else if (tid < IT * 8 + IT / 2) {                 // 4 float4s of x
        ((float4*)xaS)[tid - IT * 8] = ((const float4*)(x + 2 * i0))[tid - IT * 8];
    }
    __syncthreads();

    const int j0 = blockIdx.x * (256 * JPT) + tid * JPT;   // 2 contiguous j's
    if (j0 >= n) return;     // no barriers after this point

    float uB[JPT][QN], ssB[JPT][QN], cB[JPT][QN], snB[JPT][QN];
    float yj0[JPT], yj1[JPT];
    #pragma unroll
    for (int jj = 0; jj < JPT; ++jj) {
        const float4* fb4 = (const float4*)(fB + 32 * (j0 + jj));
        float4 a0 = fb4[0], a1 = fb4[1], a2 = fb4[2], a3 = fb4[3];
        float4 a4 = fb4[4], a5 = fb4[5], a6 = fb4[6], a7 = fb4[7];
        uB[jj][0]=a0.x; uB[jj][1]=a0.y; uB[jj][2]=a0.z; uB[jj][3]=a0.w;
        uB[jj][4]=a1.x; uB[jj][5]=a1.y; uB[jj][6]=a1.z; uB[jj][7]=a1.w;
        ssB[jj][0]=a2.x; ssB[jj][1]=a2.y; ssB[jj][2]=a2.z; ssB[jj][3]=a2.w;
        ssB[jj][4]=a3.x; ssB[jj][5]=a3.y; ssB[jj][6]=a3.z; ssB[jj][7]=a3.w;
        cB[jj][0]=a4.x; cB[jj][1]=a4.y; cB[jj][2]=a4.z; cB[jj][3]=a4.w;
        cB[jj][4]=a5.x; cB[jj][5]=a5.y; cB[jj][6]=a5.z; cB[jj][7]=a5.w;
        snB[jj][0]=a6.x; snB[jj][1]=a6.y; snB[jj][2]=a6.z; snB[jj][3]=a6.w;
        snB[jj][4]=a7.x; snB[jj][5]=a7.y; snB[jj][6]=a7.z; snB[jj][7]=a7.w;
        float2 yv = *(const float2*)(y + 2 * (j0 + jj));
        yj0[jj] = yv.x; yj1[jj] = yv.y;
    }

    const float NLOG2E = -1.4426950408889634f;

    #pragma unroll 2
    for (int ii = 0; ii < IT; ++ii) {
        int i = i0 + ii;
        if (i >= n) break;

        const float4* fa4 = (const float4*)(faS + ii * 32);
        float4 b0 = fa4[0], b1v = fa4[1], b2v = fa4[2], b3 = fa4[3];
        float4 b4 = fa4[4], b5 = fa4[5], b6 = fa4[6], b7 = fa4[7];
        float uA[QN]  = {b0.x,b0.y,b0.z,b0.w, b1v.x,b1v.y,b1v.z,b1v.w};
        float ssA[QN] = {b2v.x,b2v.y,b2v.z,b2v.w, b3.x,b3.y,b3.z,b3.w};
        float cA[QN]  = {b4.x,b4.y,b4.z,b4.w, b5.x,b5.y,b5.z,b5.w};
        float snA[QN] = {b6.x,b6.y,b6.z,b6.w, b7.x,b7.y,b7.z,b7.w};
        float xi0 = xaS[2 * ii], xi1 = xaS[2 * ii + 1];

        float d2ln[JPT];
        #pragma unroll
        for (int jj = 0; jj < JPT; ++jj) {
            float dx = xi0 - yj0[jj];
            float dy = xi1 - yj1[jj];
            d2ln[jj] = fmaf(dx, dx, dy * dy) * NLOG2E;   // -d2*log2(e)
        }

        float2 accv;
        float* accp = &accv.x;
        #pragma unroll
        for (int jj = 0; jj < JPT; ++jj) {
            float acc = 0.f;
            #pragma unroll
            for (int q = 0; q < QN; ++q) {
                float s2  = ssA[q] + ssB[jj][q];
                float inv = __builtin_amdgcn_rcpf(s2);
                float e   = __builtin_amdgcn_exp2f(d2ln[jj] * inv);
                float t   = uA[q] * uB[jj][q];
                float c   = fmaf(cA[q], cB[jj][q], snA[q] * snB[jj][q]);
                acc = fmaf(t * inv * e, c, acc);
            }
            accp[jj] = acc;
        }
        *(float2*)(out + (long)i * n + j0) = accv;
    }
}

// ---------------------------------------------------------------------------
// INSTRUMENTATION: empty kernel. 8 dispatches appended -> dur = 27.1 + 8f,
// where f = per-dispatch graph overhead. Touches nothing; deterministic.
// ---------------------------------------------------------------------------
__global__ void null_kernel() {}

extern "C" void kernel_launch(void* const* d_in, const int* in_sizes, int n_in,
                              void* d_out, int out_size, void* d_ws, size_t ws_size,
                              hipStream_t stream)
{
    const float* x  = (const float*)d_in[0];
    const float* y  = (const float*)d_in[1];
    const float* W1 = (const float*)d_in[2];
    const float* b1 = (const float*)d_in[3];
    const float* W2 = (const float*)d_in[4];
    const float* b2 = (const float*)d_in[5];
    float* out = (float*)d_out;

    int n = in_sizes[0] / NDIMS;     // 2048

    float* featX = (float*)d_ws;
    float* featY = featX + (size_t)n * 32;

    int npts = 2 * n;
    int featThreads = npts * OUTC;                    // one thread per (pt, o)
    hipLaunchKernelGGL(feat_kernel, dim3((featThreads + 255) / 256), dim3(256), 0, stream,
                       x, y, n, W1, b1, W2, b2, featX, featY);

    dim3 grid((n + 256 * JPT - 1) / (256 * JPT), (n + IT - 1) / IT);
    hipLaunchKernelGGL(pair_kernel, grid, dim3(256), 0, stream,
                       x, y, n, featX, featY, out);

    // 8 null dispatches: measures per-dispatch overhead f with 8x SNR.
    #pragma unroll
    for (int r = 0; r < 8; ++r)
        hipLaunchKernelGGL(null_kernel, dim3(1), dim3(64), 0, stream);
}

// Round 14
// 27.190 us; speedup vs baseline: 1.5883x; 1.4441x over previous
//
#include <hip/hip_runtime.h>
#include <math.h>

#define QN 8
#define NDIMS 2
#define LATENT 64
#define OUTC 32     // Q + Q + Q*NDIMS
#define IT 8        // i-rows per block tile in pair kernel
#define JPT 2       // j's per thread in pair kernel

// ---------------------------------------------------------------------------
// Phase 1: feature MLP — BYTE-IDENTICAL to round 11 (clean A/B: pair-only
// change this round).
// ---------------------------------------------------------------------------
__global__ __launch_bounds__(256) void feat_kernel(
    const float* __restrict__ x, const float* __restrict__ y, int n,
    const float* __restrict__ W1, const float* __restrict__ b1,
    const float* __restrict__ W2, const float* __restrict__ b2,
    float* __restrict__ featX, float* __restrict__ featY)
{
    const int t    = blockIdx.x * 256 + threadIdx.x;
    const int pt   = t >> 5;                 // point index (2 points per wave)
    const int o    = t & 31;                 // output unit for this lane
    const int npts = 2 * n;
    if (pt >= npts) return;

    const float* p = (pt < n) ? (x + 2 * pt) : (y + 2 * (pt - n));
    float p0 = p[0], p1 = p[1];

    const float kScale = 1.0507009873554804934193349852946f;
    const float kAlpha = 1.6732632423543772848170429916717f;

    const float4* w2v = (const float4*)(W2 + o * LATENT);
    float z0 = b2[o], z1 = 0.f, z2 = 0.f, z3 = 0.f;
    #pragma unroll
    for (int c = 0; c < LATENT / 16; ++c) {
        float hb[16];
        #pragma unroll
        for (int r = 0; r < 16; ++r) {
            int k = 16 * c + r;
            float zz = fmaf(W1[2 * k], p0, fmaf(W1[2 * k + 1], p1, b1[k]));
            hb[r] = kScale * (zz > 0.f ? zz : kAlpha * (__expf(zz) - 1.f));
        }
        float4 w0 = w2v[4 * c + 0];
        float4 w1v = w2v[4 * c + 1];
        float4 w2q = w2v[4 * c + 2];
        float4 w3 = w2v[4 * c + 3];
        z0 = fmaf(w0.x,  hb[0],  fmaf(w0.y,  hb[1],  fmaf(w0.z,  hb[2],  fmaf(w0.w,  hb[3],  z0))));
        z1 = fmaf(w1v.x, hb[4],  fmaf(w1v.y, hb[5],  fmaf(w1v.z, hb[6],  fmaf(w1v.w, hb[7],  z1))));
        z2 = fmaf(w2q.x, hb[8],  fmaf(w2q.y, hb[9],  fmaf(w2q.z, hb[10], fmaf(w2q.w, hb[11], z2))));
        z3 = fmaf(w3.x,  hb[12], fmaf(w3.y,  hb[13], fmaf(w3.z,  hb[14], fmaf(w3.w,  hb[15], z3))));
    }
    float z = (z0 + z1) + (z2 + z3);
    float av = fmaxf(z, 0.f) + __logf(1.f + __expf(-fabsf(z)));

    const int lane = threadIdx.x & 63;
    const int base = lane & 32;               // half-wave owning this point
    const int q    = lane & 7;
    float w_ = __shfl(av, base + q, 64);
    float s_ = __shfl(av, base + 8 + q, 64);
    float f0 = __shfl(av, base + 16 + 2 * q, 64);
    float f1 = __shfl(av, base + 17 + 2 * q, 64);

    if ((lane & 31) < 8) {
        const float TWO_PI  = 6.283185307179586f;
        const float ROOT4_2 = 1.18920711500272107f;   // 2^(1/4)
        float phi = fmaf(f0, p0, f1 * p1);
        float rr  = phi - floorf(phi);
        float ang = TWO_PI * rr;
        float* fo = (pt < n) ? (featX + 32 * pt) : (featY + 32 * (pt - n));
        fo[q]          = w_ * sqrtf(s_) * ROOT4_2;
        fo[QN + q]     = s_ * s_;
        fo[2 * QN + q] = __cosf(ang);
        fo[3 * QN + q] = __sinf(ang);
    }
}

// ---------------------------------------------------------------------------
// float2 packed-math helpers — goal: VOP3P v_pk_{mul,add,fma}_f32 emission.
// ---------------------------------------------------------------------------
__device__ __forceinline__ float2 f2add(float2 a, float2 b) {
    return make_float2(a.x + b.x, a.y + b.y);
}
__device__ __forceinline__ float2 f2mul(float2 a, float2 b) {
    return make_float2(a.x * b.x, a.y * b.y);
}
__device__ __forceinline__ float2 f2fma(float2 a, float2 b, float2 c) {
    return make_float2(fmaf(a.x, b.x, c.x), fmaf(a.y, b.y, c.y));
}

// ---------------------------------------------------------------------------
// Phase 2: pair_v4 — same structure as r11's pair_v3 (JPT=2, IT=8), but the
// q-loop processes q-PAIRS (q, q+4) as float2 so the compiler can emit packed
// fp32 VALU (VOP3P), halving mul/add/fma issue slots. rcp/exp2 stay scalar
// (no packed trans). Per qp-iter: ~7 packed VALU + 4 trans (was ~16 + 4).
// out[i,j] = sum_q uA*uB/s2 * exp(-d2/s2) * (cA*cB + snA*snB),  s2=ssqA+ssqB
// ---------------------------------------------------------------------------
__global__ __launch_bounds__(256) void pair_kernel(
    const float* __restrict__ x, const float* __restrict__ y, int n,
    const float* __restrict__ fA, const float* __restrict__ fB,
    float* __restrict__ out)
{
    __shared__ __align__(16) float faS[IT * 32];       // 1 KB
    __shared__ __align__(16) float xaS[IT * 2];        // 64 B

    const int tid = threadIdx.x;
    const int i0  = blockIdx.y * IT;

    if (tid < IT * 8) {                                 // 64 float4s of fA
        ((float4*)faS)[tid] = ((const float4*)(fA + (size_t)i0 * 32))[tid];
    } else if (tid < IT * 8 + IT / 2) {                 // 4 float4s of x
        ((float4*)xaS)[tid - IT * 8] = ((const float4*)(x + 2 * i0))[tid - IT * 8];
    }
    __syncthreads();

    const int j0 = blockIdx.x * (256 * JPT) + tid * JPT;   // 2 contiguous j's
    if (j0 >= n) return;     // no barriers after this point

    // B-side features as float2 q-pairs (q, q+4), static indices
    float2 uB2[JPT][4], ssB2[JPT][4], cB2[JPT][4], snB2[JPT][4];
    float yj0[JPT], yj1[JPT];
    #pragma unroll
    for (int jj = 0; jj < JPT; ++jj) {
        const float4* fb4 = (const float4*)(fB + 32 * (j0 + jj));
        float4 a0 = fb4[0], a1 = fb4[1], a2 = fb4[2], a3 = fb4[3];
        float4 a4 = fb4[4], a5 = fb4[5], a6 = fb4[6], a7 = fb4[7];
        uB2[jj][0]  = make_float2(a0.x, a1.x); uB2[jj][1]  = make_float2(a0.y, a1.y);
        uB2[jj][2]  = make_float2(a0.z, a1.z); uB2[jj][3]  = make_float2(a0.w, a1.w);
        ssB2[jj][0] = make_float2(a2.x, a3.x); ssB2[jj][1] = make_float2(a2.y, a3.y);
        ssB2[jj][2] = make_float2(a2.z, a3.z); ssB2[jj][3] = make_float2(a2.w, a3.w);
        cB2[jj][0]  = make_float2(a4.x, a5.x); cB2[jj][1]  = make_float2(a4.y, a5.y);
        cB2[jj][2]  = make_float2(a4.z, a5.z); cB2[jj][3]  = make_float2(a4.w, a5.w);
        snB2[jj][0] = make_float2(a6.x, a7.x); snB2[jj][1] = make_float2(a6.y, a7.y);
        snB2[jj][2] = make_float2(a6.z, a7.z); snB2[jj][3] = make_float2(a6.w, a7.w);
        float2 yv = *(const float2*)(y + 2 * (j0 + jj));
        yj0[jj] = yv.x; yj1[jj] = yv.y;
    }

    const float NLOG2E = -1.4426950408889634f;

    #pragma unroll 2
    for (int ii = 0; ii < IT; ++ii) {
        int i = i0 + ii;
        if (i >= n) break;

        // broadcast ds_read_b128 of this i's features (all lanes same addr)
        const float4* fa4 = (const float4*)(faS + ii * 32);
        float4 b0 = fa4[0], b1v = fa4[1], b2v = fa4[2], b3 = fa4[3];
        float4 b4 = fa4[4], b5 = fa4[5], b6 = fa4[6], b7 = fa4[7];
        float2 uA2[4]  = { make_float2(b0.x, b1v.x), make_float2(b0.y, b1v.y),
                           make_float2(b0.z, b1v.z), make_float2(b0.w, b1v.w) };
        float2 ssA2[4] = { make_float2(b2v.x, b3.x), make_float2(b2v.y, b3.y),
                           make_float2(b2v.z, b3.z), make_float2(b2v.w, b3.w) };
        float2 cA2[4]  = { make_float2(b4.x, b5.x), make_float2(b4.y, b5.y),
                           make_float2(b4.z, b5.z), make_float2(b4.w, b5.w) };
        float2 snA2[4] = { make_float2(b6.x, b7.x), make_float2(b6.y, b7.y),
                           make_float2(b6.z, b7.z), make_float2(b6.w, b7.w) };
        float xi0 = xaS[2 * ii], xi1 = xaS[2 * ii + 1];

        float d2l[JPT];
        #pragma unroll
        for (int jj = 0; jj < JPT; ++jj) {
            float dx = xi0 - yj0[jj];
            float dy = xi1 - yj1[jj];
            d2l[jj] = fmaf(dx, dx, dy * dy) * NLOG2E;   // -d2*log2(e)
        }

        float2 accv;
        float* accp = &accv.x;
        #pragma unroll
        for (int jj = 0; jj < JPT; ++jj) {
            float2 d2v  = make_float2(d2l[jj], d2l[jj]);
            float2 acc2 = make_float2(0.f, 0.f);
            #pragma unroll
            for (int qp = 0; qp < 4; ++qp) {
                float2 s2  = f2add(ssA2[qp], ssB2[jj][qp]);            // pk_add
                float2 inv = make_float2(__builtin_amdgcn_rcpf(s2.x),
                                         __builtin_amdgcn_rcpf(s2.y)); // 2x trans
                float2 ag  = f2mul(d2v, inv);                          // pk_mul
                float2 e   = make_float2(__builtin_amdgcn_exp2f(ag.x),
                                         __builtin_amdgcn_exp2f(ag.y)); // 2x trans
                float2 t   = f2mul(uA2[qp], uB2[jj][qp]);              // pk_mul
                float2 c   = f2fma(cA2[qp], cB2[jj][qp],
                                   f2mul(snA2[qp], snB2[jj][qp]));     // pk_mul+pk_fma
                float2 g   = f2mul(f2mul(t, inv), e);                  // 2x pk_mul
                acc2 = f2fma(g, c, acc2);                              // pk_fma
            }
            accp[jj] = acc2.x + acc2.y;
        }
        *(float2*)(out + (long)i * n + j0) = accv;
    }
}

extern "C" void kernel_launch(void* const* d_in, const int* in_sizes, int n_in,
                              void* d_out, int out_size, void* d_ws, size_t ws_size,
                              hipStream_t stream)
{
    const float* x  = (const float*)d_in[0];
    const float* y  = (const float*)d_in[1];
    const float* W1 = (const float*)d_in[2];
    const float* b1 = (const float*)d_in[3];
    const float* W2 = (const float*)d_in[4];
    const float* b2 = (const float*)d_in[5];
    float* out = (float*)d_out;

    int n = in_sizes[0] / NDIMS;     // 2048

    float* featX = (float*)d_ws;
    float* featY = featX + (size_t)n * 32;

    int npts = 2 * n;
    int featThreads = npts * OUTC;                    // one thread per (pt, o)
    hipLaunchKernelGGL(feat_kernel, dim3((featThreads + 255) / 256), dim3(256), 0, stream,
                       x, y, n, W1, b1, W2, b2, featX, featY);

    dim3 grid((n + 256 * JPT - 1) / (256 * JPT), (n + IT - 1) / IT);
    hipLaunchKernelGGL(pair_kernel, grid, dim3(256), 0, stream,
                       x, y, n, featX, featY, out);
}

// Round 15
// 26.691 us; speedup vs baseline: 1.6180x; 1.0187x over previous
//
#include <hip/hip_runtime.h>
#include <math.h>

#define QN 8
#define NDIMS 2
#define LATENT 64
#define OUTC 32     // Q + Q + Q*NDIMS
#define FSTR 24     // floats per point in feature buffer: [0:8) s^2 | [8:16) u*cos | [16:24) u*sin
#define IT 8        // i-rows per block tile in pair kernel
#define JPT 2       // j's per thread in pair kernel

// ---------------------------------------------------------------------------
// Phase 1: feature MLP — 64 THREADS PER POINT: thread = (pt, o, half).
//   o = output unit (32), half = k-half (2): each thread computes h[k] for
//   k in [32*half, 32*half+32) and a 32-long partial W2[o] dot; the 2 halves
//   combine with ONE shfl_xor(32). 262144 threads = 4096 waves = 4 waves/SIMD
//   (2x round-5's occupancy) at HALF the per-thread chain (32 exp, not 64).
//   No LDS, no barrier, no extra gathers vs r5 (same total W2 lines).
// Epilogue stores the FACTORIZED features (24 floats/point):
//   ssq[q] = s^2 ; vc[q] = u*cos(2pi phi) ; vs[q] = u*sin(2pi phi),
//   u = w*sqrt(s)*2^.25  =>  pair's cosine term becomes vcA*vcB + vsA*vsB.
// ---------------------------------------------------------------------------
__global__ __launch_bounds__(256) void feat_kernel(
    const float* __restrict__ x, const float* __restrict__ y, int n,
    const float* __restrict__ W1, const float* __restrict__ b1,
    const float* __restrict__ W2, const float* __restrict__ b2,
    float* __restrict__ featX, float* __restrict__ featY)
{
    const int tid  = threadIdx.x;
    const int lane = tid & 63;
    const int o    = lane & 31;               // output unit
    const int half = lane >> 5;               // k-half
    const int pt   = blockIdx.x * 4 + (tid >> 6);
    const int npts = 2 * n;
    if (pt >= npts) return;                   // grid exact for npts=4096

    const float* p = (pt < n) ? (x + 2 * pt) : (y + 2 * (pt - n));
    const float p0 = p[0], p1 = p[1];

    const float kScale = 1.0507009873554804934193349852946f;
    const float kAlpha = 1.6732632423543772848170429916717f;

    const int kbase = half * 32;
    const float4* w1v = (const float4*)(W1 + 2 * kbase);        // 16 float4
    const float4* b1v = (const float4*)(b1 + kbase);            // 8 float4
    const float4* w2v = (const float4*)(W2 + o * LATENT + kbase); // 8 float4

    float acc0 = (half == 0) ? b2[o] : 0.f;
    float acc1 = 0.f, acc2 = 0.f, acc3 = 0.f;
    #pragma unroll
    for (int g = 0; g < 8; ++g) {             // 4 h-units per group
        float4 wa = w1v[2 * g];               // W1 rows kbase+4g .. +1
        float4 wb = w1v[2 * g + 1];           // rows +2, +3
        float4 bb = b1v[g];
        float z0 = fmaf(wa.x, p0, fmaf(wa.y, p1, bb.x));
        float z1 = fmaf(wa.z, p0, fmaf(wa.w, p1, bb.y));
        float z2 = fmaf(wb.x, p0, fmaf(wb.y, p1, bb.z));
        float z3 = fmaf(wb.z, p0, fmaf(wb.w, p1, bb.w));
        float h0 = kScale * (z0 > 0.f ? z0 : kAlpha * (__expf(z0) - 1.f));
        float h1 = kScale * (z1 > 0.f ? z1 : kAlpha * (__expf(z1) - 1.f));
        float h2 = kScale * (z2 > 0.f ? z2 : kAlpha * (__expf(z2) - 1.f));
        float h3 = kScale * (z3 > 0.f ? z3 : kAlpha * (__expf(z3) - 1.f));
        float4 w2q = w2v[g];
        acc0 = fmaf(w2q.x, h0, acc0);
        acc1 = fmaf(w2q.y, h1, acc1);
        acc2 = fmaf(w2q.z, h2, acc2);
        acc3 = fmaf(w2q.w, h3, acc3);
    }
    float zsum = (acc0 + acc1) + (acc2 + acc3);
    zsum += __shfl_xor(zsum, 32, 64);         // combine the two k-halves
    // stable softplus
    float av = fmaxf(zsum, 0.f) + __logf(1.f + __expf(-fabsf(zsum)));
    // av == a[o] on every lane (both halves)

    // ---- epilogue: lanes 0..23 emit {ssq, vc, vs} for q = o&7 ----
    const int q = o & 7;
    float w_ = __shfl(av, q, 64);             // w_q
    float s_ = __shfl(av, 8 + q, 64);         // s_q
    float f0 = __shfl(av, 16 + 2 * q, 64);
    float f1 = __shfl(av, 17 + 2 * q, 64);

    float val;
    if (o < 8) {
        val = s_ * s_;                        // ssq
    } else {
        const float TWO_PI  = 6.283185307179586f;
        const float ROOT4_2 = 1.18920711500272107f;   // 2^(1/4)
        float u   = w_ * sqrtf(s_) * ROOT4_2;
        float phi = fmaf(f0, p0, f1 * p1);
        float rr  = phi - floorf(phi);        // [0,1) revolutions
        float ang = TWO_PI * rr;
        val = u * ((o < 16) ? __cosf(ang) : __sinf(ang));
    }
    if (lane < FSTR) {                        // lanes 0..23, o==lane
        float* fo = (pt < n) ? (featX + FSTR * pt) : (featY + FSTR * (pt - n));
        fo[o] = val;                          // coalesced 96B per point
    }
}

// ---------------------------------------------------------------------------
// Phase 2: pair_v5 — r11's proven structure (JPT=2, IT=8) with factorized
// features: q-term = 6 VALU + 2 trans (was 8+2); B-state and LDS stage -25%.
// out[i,j] = sum_q (inv*e) * (vcA*vcB + vsA*vsB),
//            inv = 1/(ssqA+ssqB), e = exp(-d2*inv)
// ---------------------------------------------------------------------------
__global__ __launch_bounds__(256) void pair_kernel(
    const float* __restrict__ x, const float* __restrict__ y, int n,
    const float* __restrict__ fA, const float* __restrict__ fB,
    float* __restrict__ out)
{
    __shared__ __align__(16) float faS[IT * FSTR];     // 768 B
    __shared__ __align__(16) float xaS[IT * 2];        // 64 B

    const int tid = threadIdx.x;
    const int i0  = blockIdx.y * IT;

    // ---- cooperative stage of the i-tile (coalesced float4) ----
    if (tid < IT * 6) {                                 // 48 float4s of fA
        ((float4*)faS)[tid] = ((const float4*)(fA + (size_t)i0 * FSTR))[tid];
    } else if (tid < IT * 6 + IT / 2) {                 // 4 float4s of x
        ((float4*)xaS)[tid - IT * 6] = ((const float4*)(x + 2 * i0))[tid - IT * 6];
    }
    __syncthreads();

    const int j0 = blockIdx.x * (256 * JPT) + tid * JPT;   // 2 contiguous j's
    if (j0 >= n) return;     // no barriers after this point

    // ---- B-side features for 2 j's into registers (static indices) --------
    float ssB[JPT][QN], vcB[JPT][QN], vsB[JPT][QN];
    float yj0[JPT], yj1[JPT];
    #pragma unroll
    for (int jj = 0; jj < JPT; ++jj) {
        const float4* fb4 = (const float4*)(fB + FSTR * (j0 + jj));
        float4 a0 = fb4[0], a1 = fb4[1];       // ssq
        float4 a2 = fb4[2], a3 = fb4[3];       // vc
        float4 a4 = fb4[4], a5 = fb4[5];       // vs
        ssB[jj][0]=a0.x; ssB[jj][1]=a0.y; ssB[jj][2]=a0.z; ssB[jj][3]=a0.w;
        ssB[jj][4]=a1.x; ssB[jj][5]=a1.y; ssB[jj][6]=a1.z; ssB[jj][7]=a1.w;
        vcB[jj][0]=a2.x; vcB[jj][1]=a2.y; vcB[jj][2]=a2.z; vcB[jj][3]=a2.w;
        vcB[jj][4]=a3.x; vcB[jj][5]=a3.y; vcB[jj][6]=a3.z; vcB[jj][7]=a3.w;
        vsB[jj][0]=a4.x; vsB[jj][1]=a4.y; vsB[jj][2]=a4.z; vsB[jj][3]=a4.w;
        vsB[jj][4]=a5.x; vsB[jj][5]=a5.y; vsB[jj][6]=a5.z; vsB[jj][7]=a5.w;
        float2 yv = *(const float2*)(y + 2 * (j0 + jj));
        yj0[jj] = yv.x; yj1[jj] = yv.y;
    }

    const float NLOG2E = -1.4426950408889634f;

    #pragma unroll 2
    for (int ii = 0; ii < IT; ++ii) {
        int i = i0 + ii;
        if (i >= n) break;

        // broadcast ds_read_b128 of this i's features (all lanes same addr)
        const float4* fa4 = (const float4*)(faS + ii * FSTR);
        float4 b0 = fa4[0], b1v = fa4[1];
        float4 b2v = fa4[2], b3 = fa4[3];
        float4 b4 = fa4[4], b5 = fa4[5];
        float ssA[QN] = {b0.x,b0.y,b0.z,b0.w, b1v.x,b1v.y,b1v.z,b1v.w};
        float vcA[QN] = {b2v.x,b2v.y,b2v.z,b2v.w, b3.x,b3.y,b3.z,b3.w};
        float vsA[QN] = {b4.x,b4.y,b4.z,b4.w, b5.x,b5.y,b5.z,b5.w};
        float xi0 = xaS[2 * ii], xi1 = xaS[2 * ii + 1];

        float d2ln[JPT];
        #pragma unroll
        for (int jj = 0; jj < JPT; ++jj) {
            float dx = xi0 - yj0[jj];
            float dy = xi1 - yj1[jj];
            d2ln[jj] = fmaf(dx, dx, dy * dy) * NLOG2E;   // -d2*log2(e)
        }

        float2 accv;
        float* accp = &accv.x;
        #pragma unroll
        for (int jj = 0; jj < JPT; ++jj) {
            float acc = 0.f;
            #pragma unroll
            for (int q = 0; q < QN; ++q) {
                float s2  = ssA[q] + ssB[jj][q];                   // add
                float inv = __builtin_amdgcn_rcpf(s2);             // trans
                float e   = __builtin_amdgcn_exp2f(d2ln[jj] * inv); // mul+trans
                float w   = inv * e;                               // mul
                float c   = fmaf(vcA[q], vcB[jj][q],
                                 vsA[q] * vsB[jj][q]);             // mul+fma
                acc = fmaf(w, c, acc);                             // fma
            }
            accp[jj] = acc;
        }
        *(float2*)(out + (long)i * n + j0) = accv;
    }
}

extern "C" void kernel_launch(void* const* d_in, const int* in_sizes, int n_in,
                              void* d_out, int out_size, void* d_ws, size_t ws_size,
                              hipStream_t stream)
{
    const float* x  = (const float*)d_in[0];
    const float* y  = (const float*)d_in[1];
    const float* W1 = (const float*)d_in[2];
    const float* b1 = (const float*)d_in[3];
    const float* W2 = (const float*)d_in[4];
    const float* b2 = (const float*)d_in[5];
    float* out = (float*)d_out;

    int n = in_sizes[0] / NDIMS;     // 2048

    float* featX = (float*)d_ws;
    float* featY = featX + (size_t)n * FSTR;

    int npts = 2 * n;
    // 64 threads per point, 4 points per 256-thread block
    hipLaunchKernelGGL(feat_kernel, dim3((npts + 3) / 4), dim3(256), 0, stream,
                       x, y, n, W1, b1, W2, b2, featX, featY);

    dim3 grid((n + 256 * JPT - 1) / (256 * JPT), (n + IT - 1) / IT);
    hipLaunchKernelGGL(pair_kernel, grid, dim3(256), 0, stream,
                       x, y, n, featX, featY, out);
}